// Round 6
// baseline (4258.028 us; speedup 1.0000x reference)
//
#include <hip/hip_runtime.h>
#include <cstdint>
#include <cstddef>

#define Tt  512
#define Kk  8
#define NI  256
#define UN  256
#define G4  1024   // 4*UN

typedef unsigned short ushort_t;
typedef __attribute__((ext_vector_type(8))) short short8;
typedef __attribute__((ext_vector_type(4))) float f32x4;

__global__ void zero_ws(unsigned int* p, int n) {
    int stride = gridDim.x * blockDim.x;
    for (int i = blockIdx.x * blockDim.x + threadIdx.x; i < n; i += stride)
        p[i] = 0u;
}

__device__ __forceinline__ ushort_t f2bf(float x) {
    union { float f; unsigned int u; } v; v.f = x;
    unsigned int r = v.u + 0x7FFFu + ((v.u >> 16) & 1u);
    return (ushort_t)(r >> 16);
}

__device__ __forceinline__ float hsig(float z) {
    return __builtin_amdgcn_fmed3f(fmaf(z, 0.2f, 0.5f), 0.0f, 1.0f);
}

__device__ __forceinline__ float fast_tanh(float x) {
    float e = __expf(2.0f * x);
    return 1.0f - 2.0f * __builtin_amdgcn_rcpf(e + 1.0f);
}

// LDS-only barrier: waits DS ops, does NOT drain vmcnt (out stores and xw
// prefetch loads stay in flight across it). sched_barrier(0) per rule #18.
__device__ __forceinline__ void lds_barrier() {
    asm volatile("s_waitcnt lgkmcnt(0)" ::: "memory");
    __builtin_amdgcn_sched_barrier(0);
    __builtin_amdgcn_s_barrier();
    __builtin_amdgcn_sched_barrier(0);
    asm volatile("" ::: "memory");
}

// ---------------- Phase A: xw[t'][b*8+k][col] = bias + x@W (unchanged) ----------------
__global__ __launch_bounds__(256) void xw_gemm(const float* __restrict__ x,
                                               const float* __restrict__ W,
                                               const float* __restrict__ bias,
                                               float* __restrict__ xw, int t0) {
    __shared__ __align__(16) float At[16][132];
    __shared__ __align__(16) float Bt[16][132];

    const int k  = blockIdx.z;
    const int C0 = blockIdx.x * 128;
    const int R0 = blockIdx.y * 128;
    const int tid = threadIdx.x;
    const int tx = tid & 15, ty = tid >> 4;

    float acc[8][8];
#pragma unroll
    for (int i = 0; i < 8; i++)
#pragma unroll
        for (int j = 0; j < 8; j++) acc[i][j] = 0.0f;

    const int lakk = tid & 15, larl = tid >> 4;
    const int lbc  = tid & 127, lbk = tid >> 7;

    for (int kt = 0; kt < NI; kt += 16) {
#pragma unroll
        for (int ps = 0; ps < 8; ps++) {
            int rloc = larl + ps * 16;
            int r = R0 + rloc;
            int b = r & 15, tp = r >> 4;
            At[lakk][rloc] = x[(((size_t)b * Tt + (t0 + tp)) * Kk + k) * NI + kt + lakk];
        }
#pragma unroll
        for (int ps = 0; ps < 8; ps++) {
            int kkr = lbk + ps * 2;
            Bt[kkr][lbc] = W[((size_t)k * NI + kt + kkr) * G4 + C0 + lbc];
        }
        __syncthreads();
#pragma unroll
        for (int kk = 0; kk < 16; kk++) {
            const float4* Ar = (const float4*)&At[kk][ty * 8];
            const float4* Br = (const float4*)&Bt[kk][tx * 8];
            float4 a0 = Ar[0], a1 = Ar[1];
            float4 b0 = Br[0], b1 = Br[1];
            float a[8] = {a0.x, a0.y, a0.z, a0.w, a1.x, a1.y, a1.z, a1.w};
            float bb[8] = {b0.x, b0.y, b0.z, b0.w, b1.x, b1.y, b1.z, b1.w};
#pragma unroll
            for (int i = 0; i < 8; i++)
#pragma unroll
                for (int j = 0; j < 8; j++)
                    acc[i][j] = fmaf(a[i], bb[j], acc[i][j]);
        }
        __syncthreads();
    }
    float bv[8];
#pragma unroll
    for (int j = 0; j < 8; j++) bv[j] = bias[(size_t)k * G4 + C0 + tx * 8 + j];
#pragma unroll
    for (int i = 0; i < 8; i++) {
        int r = R0 + ty * 8 + i;
        int b = r & 15, tp = r >> 4;
        float* op = xw + ((size_t)tp * 128 + b * 8 + k) * G4 + C0 + tx * 8;
#pragma unroll
        for (int j = 0; j < 8; j++) op[j] = acc[i][j] + bv[j];
    }
}

// ---------------- Phase B: MFMA recurrence, BATCH-split, ZERO exchange ----------------
// Batches are independent in the recurrence (h_t[b] depends only on h_{t-1}[b]).
// 16 wgs x 512 threads: k = bid&7, bh = bid>>3 (batch half). Each WG computes
// ALL 256 units x 4 gates for its 8 batches -> no inter-WG communication for
// the whole sequence. Full U[k] (bf16) lives in registers: bfr[2][4][8] = 64
// short8 = 256 regs/lane (static indices only, rule #20; B-operand may sit in
// AGPRs — gfx950 MFMA reads A/B from either). A-tile rows 8-15 (absent
// batches) stay ZERO in LDS -> 2x MFMA count, trivially cheap vs the removed
// exchange (polls/publishes/spins were ~3000 cy/step).
// Valid C/D rows 0-7 live in lanes 0-31; __shfl_xor(.,32) redistributes the
// second unit-half so all 64 lanes activate 4 gate-groups each.
// One lgkm-only barrier per step; out stores + xw loads never drained in-loop.
__global__ __launch_bounds__(512, 1) void lstm_mfma(
    const float* __restrict__ xw,        // [TC][128][1024]
    const float* __restrict__ U,         // [8][256][1024] fp32
    float* __restrict__ out,             // [16][512][8][256]
    ushort_t* __restrict__ hstate,       // [8][2][8][256] bf16
    float* __restrict__ cstate,          // [8][2][512][4] fp32
    int t0, int TC) {
    const int tid  = threadIdx.x;
    const int lane = tid & 63;
    const int w    = tid >> 6;        // wave 0..7: unit blocks {2w, 2w+1}
    const int k    = blockIdx.x & 7;
    const int bh   = blockIdx.x >> 3; // batch half 0/1
    const int l15  = lane & 15, quad = lane >> 4;

    __shared__ __align__(16) ushort_t hfr[2][4096];   // A-frag LDS, dbuf, swizzled

    // post-redistribution identity: thread owns (b = bl+r, u = uu), all 4 gates
    const int bl = (quad & 1) * 4;                    // local batch base (+r)
    const int uu = 32 * w + 16 * (quad >> 1) + l15;   // unit 0..255

    // ---- one-time: full U[k] as B-fragments (bf16), 256 regs/lane ----
    short8 bfr[2][4][8];                              // [unit-half][gate][K-block]
    const size_t Ubase = (size_t)k * (256 * 1024);
#pragma unroll
    for (int hh = 0; hh < 2; hh++) {
#pragma unroll
        for (int gg = 0; gg < 4; gg++) {
            const int col = gg * 256 + 32 * w + 16 * hh + l15;
#pragma unroll
            for (int q = 0; q < 8; q++) {
                short8 v;
#pragma unroll
                for (int j = 0; j < 8; j++) {
                    int kk = q * 32 + quad * 8 + j;
                    v[j] = (short)f2bf(U[Ubase + (size_t)kk * 1024 + col]);
                }
                bfr[hh][gg][q] = v;
            }
        }
    }

    // c-state
    float cc[4];
    const size_t cbase = (((size_t)(k * 2 + bh)) * 512 + tid) * 4;
#pragma unroll
    for (int r = 0; r < 4; r++) cc[r] = cstate[cbase + r];

    // ---- zero A-frag LDS (rows 8-15 remain zero forever), then initial h ----
    {
        ushort_t* hz = &hfr[0][0];
        for (int i = tid; i < 2 * 4096; i += 512) hz[i] = 0;
    }
    __syncthreads();
    {
        // thread scatters its own (b, u) h values: identity == scatter targets
        const int q = uu >> 5, kk = uu & 31;
        const int j = kk & 7, lnb = 16 * (kk >> 3);
#pragma unroll
        for (int r = 0; r < 4; r++) {
            ushort_t hv = hstate[((size_t)(k * 2 + bh) * 8 + bl + r) * 256 + uu];
            int ch = q * 64 + (bl + r) + lnb;
            ch ^= ((ch >> 4) & 3) << 1;               // swizzle (involution)
            hfr[0][ch * 8 + j] = hv;
        }
    }
    __syncthreads();

    int p = 0;
#pragma unroll 1
    for (int t = 0; t < TC; t++) {
        const int g = t0 + t;

        // ---- xw loads for THIS step (consumed after MFMA ~600cy later) ----
        float xwv[4][4];
#pragma unroll
        for (int gg = 0; gg < 4; gg++)
#pragma unroll
            for (int r = 0; r < 4; r++)
                xwv[gg][r] = xw[((size_t)t * 128 + (bh * 8 + bl + r) * 8 + k) * 1024
                                + gg * 256 + uu];

        // ---- z = h @ U : 64 MFMAs (8 K-blocks x 2 unit-halves x 4 gates) ----
        f32x4 acc[2][4];
        const f32x4 zv = {0.f, 0.f, 0.f, 0.f};
#pragma unroll
        for (int hh = 0; hh < 2; hh++)
#pragma unroll
            for (int gg = 0; gg < 4; gg++) acc[hh][gg] = zv;
#pragma unroll
        for (int q = 0; q < 8; q++) {
            int ch = q * 64 + (lane ^ (quad << 1));
            short8 af = *(const short8*)&hfr[p][ch * 8];
#pragma unroll
            for (int hh = 0; hh < 2; hh++)
#pragma unroll
                for (int gg = 0; gg < 4; gg++)
                    acc[hh][gg] = __builtin_amdgcn_mfma_f32_16x16x32_bf16(
                        af, bfr[hh][gg][q], acc[hh][gg], 0, 0, 0);
        }

        // ---- redistribute unit-half B to lanes 32-63, select, add xw ----
        float z[4][4];
#pragma unroll
        for (int gg = 0; gg < 4; gg++)
#pragma unroll
            for (int r = 0; r < 4; r++) {
                float bswap = __shfl_xor(acc[1][gg][r], 32);
                z[gg][r] = (quad >= 2 ? bswap : acc[0][gg][r]) + xwv[gg][r];
            }

        // ---- activation + c/h update, out store (free-flying) ----
        float hn[4];
#pragma unroll
        for (int r = 0; r < 4; r++) {
            float av = fast_tanh(z[0][r]);
            float iv = hsig(z[1][r]), fv = hsig(z[2][r]), ov = hsig(z[3][r]);
            float cn = av * iv + fv * cc[r];
            cc[r] = cn;
            hn[r] = ov * fast_tanh(cn);
            out[(((size_t)(bh * 8 + bl + r) * Tt + g) * Kk + k) * UN + uu] = hn[r];
        }

        if (t + 1 < TC) {
            // scatter h_{t+1-input} -> hfr[p^1]; ONE lgkm-only barrier per step
            const int pn = p ^ 1;
            const int q = uu >> 5, kk = uu & 31;
            const int j = kk & 7, lnb = 16 * (kk >> 3);
#pragma unroll
            for (int r = 0; r < 4; r++) {
                int ch = q * 64 + (bl + r) + lnb;
                ch ^= ((ch >> 4) & 3) << 1;
                hfr[pn][ch * 8 + j] = f2bf(hn[r]);
            }
            lds_barrier();
            p = pn;
        } else {
            // chunk end: persist state
#pragma unroll
            for (int r = 0; r < 4; r++) {
                hstate[((size_t)(k * 2 + bh) * 8 + bl + r) * 256 + uu] = f2bf(hn[r]);
                cstate[cbase + r] = cc[r];
            }
        }
    }
}

extern "C" void kernel_launch(void* const* d_in, const int* in_sizes, int n_in,
                              void* d_out, int out_size, void* d_ws, size_t ws_size,
                              hipStream_t stream) {
    const float* x    = (const float*)d_in[0];
    const float* W    = (const float*)d_in[1];
    const float* U    = (const float*)d_in[2];
    const float* bias = (const float*)d_in[3];
    float* out = (float*)d_out;

    // tail state: cstate 128KB | hstate 64KB   (hbuf eliminated — no exchange)
    const size_t TAIL = 131072 + 65536;  // 196608 B
    int TC = 16;
    const int cands[6] = {512, 256, 128, 64, 32, 16};
    for (int ci = 0; ci < 6; ci++) {
        size_t need = (size_t)cands[ci] * 128 * 1024 * 4 + TAIL;
        if (need <= ws_size) { TC = cands[ci]; break; }
    }

    float* xw = (float*)d_ws;
    char* p = (char*)d_ws + (size_t)TC * 128 * 1024 * 4;
    float*    cstate = (float*)p;     p += 131072;
    ushort_t* hstate = (ushort_t*)p;

    zero_ws<<<dim3(128), dim3(256), 0, stream>>>((unsigned int*)cstate,
                                                 (int)(TAIL / 4));

    for (int t0 = 0; t0 < Tt; t0 += TC) {
        xw_gemm<<<dim3(G4 / 128, TC * 16 / 128, Kk), dim3(256), 0, stream>>>(
            x, W, bias, xw, t0);
        lstm_mfma<<<dim3(16), dim3(512), 0, stream>>>(
            xw, U, out, hstate, cstate, t0, TC);
    }
}

// Round 7
// 2342.161 us; speedup vs baseline: 1.8180x; 1.8180x over previous
//
#include <hip/hip_runtime.h>
#include <cstdint>
#include <cstddef>

#define Tt  512
#define Kk  8
#define NI  256
#define UN  256
#define G4  1024   // 4*UN

typedef unsigned short ushort_t;
typedef __attribute__((ext_vector_type(8))) short short8;
typedef __attribute__((ext_vector_type(4))) float f32x4;

__global__ void zero_ws(unsigned int* p, int n) {
    int stride = gridDim.x * blockDim.x;
    for (int i = blockIdx.x * blockDim.x + threadIdx.x; i < n; i += stride)
        p[i] = 0u;
}

__device__ __forceinline__ ushort_t f2bf(float x) {
    union { float f; unsigned int u; } v; v.f = x;
    unsigned int r = v.u + 0x7FFFu + ((v.u >> 16) & 1u);
    return (ushort_t)(r >> 16);
}

__device__ __forceinline__ float hsig(float z) {
    return __builtin_amdgcn_fmed3f(fmaf(z, 0.2f, 0.5f), 0.0f, 1.0f);
}

__device__ __forceinline__ float fast_tanh(float x) {
    float e = __expf(2.0f * x);
    return 1.0f - 2.0f * __builtin_amdgcn_rcpf(e + 1.0f);
}

// LDS-only barrier: waits DS ops, does NOT drain vmcnt. sched_barrier(0)
// fences per methodology rule #18 (hipcc hoists reg-only MFMA past inline-asm
// lgkmcnt waits otherwise).
__device__ __forceinline__ void lds_barrier() {
    asm volatile("s_waitcnt lgkmcnt(0)" ::: "memory");
    __builtin_amdgcn_sched_barrier(0);
    __builtin_amdgcn_s_barrier();
    __builtin_amdgcn_sched_barrier(0);
    asm volatile("" ::: "memory");
}

// ---------------- Phase A: xw[t'][b*8+k][col] = bias + x@W (unchanged) ----------------
__global__ __launch_bounds__(256) void xw_gemm(const float* __restrict__ x,
                                               const float* __restrict__ W,
                                               const float* __restrict__ bias,
                                               float* __restrict__ xw, int t0) {
    __shared__ __align__(16) float At[16][132];
    __shared__ __align__(16) float Bt[16][132];

    const int k  = blockIdx.z;
    const int C0 = blockIdx.x * 128;
    const int R0 = blockIdx.y * 128;
    const int tid = threadIdx.x;
    const int tx = tid & 15, ty = tid >> 4;

    float acc[8][8];
#pragma unroll
    for (int i = 0; i < 8; i++)
#pragma unroll
        for (int j = 0; j < 8; j++) acc[i][j] = 0.0f;

    const int lakk = tid & 15, larl = tid >> 4;
    const int lbc  = tid & 127, lbk = tid >> 7;

    for (int kt = 0; kt < NI; kt += 16) {
#pragma unroll
        for (int ps = 0; ps < 8; ps++) {
            int rloc = larl + ps * 16;
            int r = R0 + rloc;
            int b = r & 15, tp = r >> 4;
            At[lakk][rloc] = x[(((size_t)b * Tt + (t0 + tp)) * Kk + k) * NI + kt + lakk];
        }
#pragma unroll
        for (int ps = 0; ps < 8; ps++) {
            int kkr = lbk + ps * 2;
            Bt[kkr][lbc] = W[((size_t)k * NI + kt + kkr) * G4 + C0 + lbc];
        }
        __syncthreads();
#pragma unroll
        for (int kk = 0; kk < 16; kk++) {
            const float4* Ar = (const float4*)&At[kk][ty * 8];
            const float4* Br = (const float4*)&Bt[kk][tx * 8];
            float4 a0 = Ar[0], a1 = Ar[1];
            float4 b0 = Br[0], b1 = Br[1];
            float a[8] = {a0.x, a0.y, a0.z, a0.w, a1.x, a1.y, a1.z, a1.w};
            float bb[8] = {b0.x, b0.y, b0.z, b0.w, b1.x, b1.y, b1.z, b1.w};
#pragma unroll
            for (int i = 0; i < 8; i++)
#pragma unroll
                for (int j = 0; j < 8; j++)
                    acc[i][j] = fmaf(a[i], bb[j], acc[i][j]);
        }
        __syncthreads();
    }
    float bv[8];
#pragma unroll
    for (int j = 0; j < 8; j++) bv[j] = bias[(size_t)k * G4 + C0 + tx * 8 + j];
#pragma unroll
    for (int i = 0; i < 8; i++) {
        int r = R0 + ty * 8 + i;
        int b = r & 15, tp = r >> 4;
        float* op = xw + ((size_t)tp * 128 + b * 8 + k) * G4 + C0 + tx * 8;
#pragma unroll
        for (int j = 0; j < 8; j++) op[j] = acc[i][j] + bv[j];
    }
}

// ---------------- Phase B: MFMA recurrence, 2 WGs/k, BATCH-COHORT pipeline ----------------
// 16 wgs x 512 threads: k = bid&7, uh = bid>>3. WG uh owns output units
// [uh*128,+128) x 4 gates for all 16 batches; U-half = bfr[4][8] = 128 regs
// (static indices, rule #20). The exchange (peer's h-half) is MANDATORY (full
// U = 512KB = entire CU register file), so instead of shrinking it we take it
// OFF the critical path: batches split into cohort 0 (tile rows 0-7) and
// cohort 1 (rows 8-15), advanced on ALTERNATE slots. While cohort A's publish
// crosses the fabric (~600cy agent scope), the WG runs cohort B's slot
// (~800cy) -> A's check hits on the first poll. Inactive cohort's z in each
// full-tile MFMA pass is discarded (2x MFMA work, cheap vs the latency
// hidden). Polls for slot s+1 are issued BEFORE the MFMA block so their
// latency hides under it; compiler emits counted vmcnt so the check waits
// only for the polls. 2 lgkm-only barriers/slot: B1 (pre-MFMA: orders
// peer+own scatters), B2 (post-MFMA: protects rows from next scatter-own).
// Liveness: 2-deep parity per cohort; publish of step T+2 data requires
// consuming peer's T+1 data which requires peer consumed our T data.
__global__ __launch_bounds__(512, 2) void lstm_mfma(
    const float* __restrict__ xw,        // [TC][128][1024]
    const float* __restrict__ U,         // [8][256][1024] fp32
    float* __restrict__ out,             // [16][512][8][256]
    ushort_t* __restrict__ hstate,       // [8][2][16][128] bf16
    float* __restrict__ cstate,          // [16][2048] fp32
    unsigned int* __restrict__ hbuf,     // [2 par][8 k][2 coh][2 uh][1024] tagged u32
    int t0, int TC) {
    const int tid  = threadIdx.x;
    const int lane = tid & 63;
    const int w    = tid >> 6;
    const int k    = blockIdx.x & 7;
    const int uh   = blockIdx.x >> 3;
    const int ph   = uh ^ 1;
    const int l15  = lane & 15, quad = lane >> 4;
    const int lc   = quad >> 1;                 // lane's cohort (b 0-7 vs 8-15)
    const int uu   = uh * 128 + w * 16 + l15;   // owned output unit (global)

    __shared__ __align__(16) ushort_t hfr[4096];   // A-frag tile [K=256]x[16b], swizzled

    // ---- one-time: B-frags of own U column-half (bf16), 128 regs ----
    short8 bfr[4][8];
    const size_t Ubase = (size_t)k * (256 * 1024);
#pragma unroll
    for (int gg = 0; gg < 4; gg++) {
        const int col = gg * 256 + uu;
#pragma unroll
        for (int q = 0; q < 8; q++) {
            short8 v;
#pragma unroll
            for (int j = 0; j < 8; j++) {
                int kk = q * 32 + quad * 8 + j;
                v[j] = (short)f2bf(U[Ubase + (size_t)kk * 1024 + col]);
            }
            bfr[gg][q] = v;
        }
    }

    // c-state: thread owns (b = quad*4+r, u = uu)
    float cc[4];
    const size_t cbase = ((size_t)(k * 2 + uh)) * 2048 + (size_t)tid * 4;
#pragma unroll
    for (int r = 0; r < 4; r++) cc[r] = cstate[cbase + r];

    // ---- initial full-h scatter: hstate[k] -> hfr (swizzled) ----
    {
        const ushort_t* hs = hstate + (size_t)k * 4096;
#pragma unroll
        for (int i = 0; i < 8; i++) {
            int e = tid + 512 * i;                 // e = half*2048 + b*128 + ul
            int b = (e >> 7) & 15;
            int u = (e >> 11) * 128 + (e & 127);
            int q = u >> 5, j = u & 7;
            int ch = q * 64 + (b + 16 * ((u & 31) >> 3));
            ch ^= ((ch >> 4) & 3) << 1;
            hfr[ch * 8 + j] = hs[e];
        }
    }
    __syncthreads();

    // xw for step 0 (all lanes; each lane only ever needs its own batches)
    float xwn[4][4];
#pragma unroll
    for (int gg = 0; gg < 4; gg++)
#pragma unroll
        for (int r = 0; r < 4; r++)
            xwn[gg][r] = xw[((size_t)0 * 128 + (quad * 4 + r) * 8 + k) * 1024
                            + gg * 256 + uu];

    unsigned int pv0 = 0, pv1 = 0;
    const int TC2 = 2 * TC;

#pragma unroll 1
    for (int s = 0; s < TC2; s++) {
        const int c   = s & 1;          // active cohort this slot
        const int tau = s >> 1;         // its step index within chunk
        const int g   = t0 + tau;

        // ---- detect cohort-c peer half (polls issued at slot s-1) ----
        if (tau > 0) {
            const unsigned int tg = (unsigned int)g & 0xFFFFu;
            const unsigned int* ps = hbuf
                + ((((size_t)(g & 1) * 8 + k) * 2 + c) * 2 + ph) * 1024;
            for (;;) {
                if (((pv0 & 0xFFFFu) == tg) & ((pv1 & 0xFFFFu) == tg)) break;
                pv0 = __hip_atomic_load(&ps[tid],
                                        __ATOMIC_RELAXED, __HIP_MEMORY_SCOPE_AGENT);
                pv1 = __hip_atomic_load(&ps[tid + 512],
                                        __ATOMIC_RELAXED, __HIP_MEMORY_SCOPE_AGENT);
            }
            {   // scatter the 2 received words (static, no dyn indexing)
                int m0 = tid;
                int b0 = c * 8 + (m0 >> 7), u0 = ph * 128 + (m0 & 127);
                int ch0 = (u0 >> 5) * 64 + (b0 + 16 * ((u0 & 31) >> 3));
                ch0 ^= ((ch0 >> 4) & 3) << 1;
                hfr[ch0 * 8 + (u0 & 7)] = (ushort_t)(pv0 >> 16);
                int m1 = tid + 512;
                int b1 = c * 8 + (m1 >> 7), u1 = ph * 128 + (m1 & 127);
                int ch1 = (u1 >> 5) * 64 + (b1 + 16 * ((u1 & 31) >> 3));
                ch1 ^= ((ch1 >> 4) & 3) << 1;
                hfr[ch1 * 8 + (u1 & 7)] = (ushort_t)(pv1 >> 16);
            }
        }

        lds_barrier();   // B1: peer-scatter (this slot) + own-scatter (s-1) -> MFMA

        // ---- issue polls for slot s+1's cohort (latency hides under MFMA) ----
        if (s + 1 < TC2 && ((s + 1) >> 1) > 0) {
            const int c1 = (s + 1) & 1;
            const int g1 = t0 + ((s + 1) >> 1);
            const unsigned int* ps = hbuf
                + ((((size_t)(g1 & 1) * 8 + k) * 2 + c1) * 2 + ph) * 1024;
            pv0 = __hip_atomic_load(&ps[tid],
                                    __ATOMIC_RELAXED, __HIP_MEMORY_SCOPE_AGENT);
            pv1 = __hip_atomic_load(&ps[tid + 512],
                                    __ATOMIC_RELAXED, __HIP_MEMORY_SCOPE_AGENT);
        }

        // ---- full-tile MFMA: z for both cohorts (inactive half discarded) ----
        f32x4 acc[4];
        const f32x4 zv = {0.f, 0.f, 0.f, 0.f};
#pragma unroll
        for (int gg = 0; gg < 4; gg++) acc[gg] = zv;
#pragma unroll
        for (int q = 0; q < 8; q++) {
            int ch = q * 64 + (lane ^ (quad << 1));
            short8 af = *(const short8*)&hfr[ch * 8];
#pragma unroll
            for (int gg = 0; gg < 4; gg++)
                acc[gg] = __builtin_amdgcn_mfma_f32_16x16x32_bf16(af, bfr[gg][q],
                                                                  acc[gg], 0, 0, 0);
        }

        lds_barrier();   // B2: all MFMA LDS reads done before scatter-own below

        // ---- active cohort lanes: act, update, out, publish/persist ----
        if (lc == c) {
            float hn[4];
#pragma unroll
            for (int r = 0; r < 4; r++) {
                float z0 = acc[0][r] + xwn[0][r];
                float z1 = acc[1][r] + xwn[1][r];
                float z2 = acc[2][r] + xwn[2][r];
                float z3 = acc[3][r] + xwn[3][r];
                float av = fast_tanh(z0);
                float iv = hsig(z1), fv = hsig(z2), ov = hsig(z3);
                float cn = av * iv + fv * cc[r];
                cc[r] = cn;
                hn[r] = ov * fast_tanh(cn);
                int b = quad * 4 + r;
                out[(((size_t)b * Tt + g) * Kk + k) * UN + uu] = hn[r];
            }

            if (tau + 1 < TC) {
                // publish own half (tag g+1) for peer's next cohort-c slot
                const unsigned int tg = (unsigned int)(g + 1) & 0xFFFFu;
                unsigned int* dst = hbuf
                    + ((((size_t)((g + 1) & 1) * 8 + k) * 2 + lc) * 2 + uh) * 1024
                    + (uu & 127);
#pragma unroll
                for (int r = 0; r < 4; r++) {
                    unsigned int pvv = ((unsigned int)f2bf(hn[r]) << 16) | tg;
                    __hip_atomic_store(&dst[((quad * 4 + r) & 7) * 128], pvv,
                                       __ATOMIC_RELAXED, __HIP_MEMORY_SCOPE_AGENT);
                }
                // scatter own half -> hfr (read by this cohort's slot s+2)
                const int q = uu >> 5, kk2 = uu & 31;
                const int j = kk2 & 7, lnb = 16 * (kk2 >> 3);
#pragma unroll
                for (int r = 0; r < 4; r++) {
                    int b = quad * 4 + r;
                    int ch = q * 64 + b + lnb;
                    ch ^= ((ch >> 4) & 3) << 1;
                    hfr[ch * 8 + j] = f2bf(hn[r]);
                }
                // xw for this cohort's next step (used at slot s+2)
#pragma unroll
                for (int gg = 0; gg < 4; gg++)
#pragma unroll
                    for (int r = 0; r < 4; r++)
                        xwn[gg][r] = xw[((size_t)(tau + 1) * 128 + (quad * 4 + r) * 8 + k) * 1024
                                        + gg * 256 + uu];
            } else {
                // cohort's final step this chunk: persist state
#pragma unroll
                for (int r = 0; r < 4; r++) {
                    int b = quad * 4 + r;
                    hstate[(size_t)k * 4096 + (size_t)uh * 2048 + b * 128 + (uu & 127)]
                        = f2bf(hn[r]);
                    cstate[cbase + r] = cc[r];
                }
            }
        }
    }
}

extern "C" void kernel_launch(void* const* d_in, const int* in_sizes, int n_in,
                              void* d_out, int out_size, void* d_ws, size_t ws_size,
                              hipStream_t stream) {
    const float* x    = (const float*)d_in[0];
    const float* W    = (const float*)d_in[1];
    const float* U    = (const float*)d_in[2];
    const float* bias = (const float*)d_in[3];
    float* out = (float*)d_out;

    // tail state: cstate 128KB | hstate 64KB | hbuf(tagged u32) 256KB
    const size_t TAIL = 131072 + 65536 + 262144;  // 458752 B
    int TC = 16;
    const int cands[6] = {512, 256, 128, 64, 32, 16};
    for (int ci = 0; ci < 6; ci++) {
        size_t need = (size_t)cands[ci] * 128 * 1024 * 4 + TAIL;
        if (need <= ws_size) { TC = cands[ci]; break; }
    }

    float* xw = (float*)d_ws;
    char* p = (char*)d_ws + (size_t)TC * 128 * 1024 * 4;
    float*        cstate = (float*)p;         p += 131072;
    ushort_t*     hstate = (ushort_t*)p;      p += 65536;
    unsigned int* hbuf   = (unsigned int*)p;

    zero_ws<<<dim3(128), dim3(256), 0, stream>>>((unsigned int*)cstate,
                                                 (int)(TAIL / 4));

    for (int t0 = 0; t0 < Tt; t0 += TC) {
        xw_gemm<<<dim3(G4 / 128, TC * 16 / 128, Kk), dim3(256), 0, stream>>>(
            x, W, bias, xw, t0);
        lstm_mfma<<<dim3(16), dim3(512), 0, stream>>>(
            xw, U, out, hstate, cstate, hbuf, t0, TC);
    }
}